// Round 3
// baseline (144.679 us; speedup 1.0000x reference)
//
#include <hip/hip_runtime.h>
#include <cmath>

#define EMBED   1024
#define EPB     8
#define NB      64
#define KTOP    2

// ---------------------------------------------------------------------------
// Kernel A: reciprocal L2 norms of the 512 key rows + zero bucket counters.
// ---------------------------------------------------------------------------
__global__ void key_rnorm_kernel(const float* __restrict__ ek,
                                 float* __restrict__ rnorm,
                                 int* __restrict__ cnt, int nrows) {
    if (blockIdx.x == 0 && threadIdx.x < NB) cnt[threadIdx.x] = 0;
    int wave = (int)((blockIdx.x * blockDim.x + threadIdx.x) >> 6);
    int lane = threadIdx.x & 63;
    if (wave >= nrows) return;
    const float4* row = (const float4*)(ek + (size_t)wave * EMBED);
    float s = 0.f;
#pragma unroll
    for (int c = 0; c < 4; ++c) {
        float4 v = row[c * 64 + lane];
        s += v.x * v.x + v.y * v.y + v.z * v.z + v.w * v.w;
    }
#pragma unroll
    for (int off = 32; off; off >>= 1) s += __shfl_xor(s, off, 64);
    if (lane == 0) rnorm[wave] = 1.0f / fmaxf(sqrtf(s), 1e-12f);
}

// ---------------------------------------------------------------------------
// Kernel B: bucket compaction. list[b*ntok + slot] = token. Order within a
// bucket is nondeterministic but irrelevant: results are written per-token.
// ---------------------------------------------------------------------------
__global__ void compact_kernel(const int* __restrict__ op_id,
                               int* __restrict__ cnt,
                               int* __restrict__ list, int ntok) {
    int t = blockIdx.x * blockDim.x + threadIdx.x;
    if (t >= ntok) return;
    int b = op_id[t];
    b = min(max(b, 0), NB - 1);
    int slot = atomicAdd(&cnt[b], 1);
    list[(size_t)b * ntok + slot] = t;
}

// ---------------------------------------------------------------------------
// Kernel C: bucket-pinned router. 8 blocks per bucket, 4 waves per block.
// Each wave holds its bucket's 8 keys in REGISTERS (lane owns element slice
// {c*64+lane : c=0..3} of each key -> 32 float4 = 128 VGPRs), then streams
// its share of the bucket's tokens: load h row (coalesced 4 KB), 9 dots,
// 6-step butterfly, epilogue on lane 0. Key global traffic: 32 KB/block
// (vs 32 KB/token before) -> no more L1 thrash; floor is h streaming.
// ---------------------------------------------------------------------------
__global__ __launch_bounds__(256, 1) void router_kernel(
        const float* __restrict__ h,
        const float* __restrict__ ek,
        const float* __restrict__ rk,
        const int*   __restrict__ cnt,
        const int*   __restrict__ list,
        float* __restrict__ out_gid,
        float* __restrict__ out_w,
        int ntok) {
    const int b    = blockIdx.x >> 3;        // bucket
    const int part = blockIdx.x & 7;         // block within bucket
    const int wv   = threadIdx.x >> 6;       // wave in block (0..3)
    const int lane = threadIdx.x & 63;
    const int q    = part * 4 + wv;          // wave id within bucket (0..31)

    const int n = cnt[b];
    if (q * 1 >= n && q >= n) { /* still need uniform exit */ }
    if (n == 0) return;

    // --- load this bucket's 8 normalized-key slices into registers ---
    const float4* k4 = (const float4*)ek + (size_t)b * (EPB * 256);
    float4 kv[EPB][4];
#pragma unroll
    for (int e = 0; e < EPB; ++e)
#pragma unroll
        for (int c = 0; c < 4; ++c)
            kv[e][c] = k4[e * 256 + c * 64 + lane];

    float rke[EPB];
#pragma unroll
    for (int e = 0; e < EPB; ++e) rke[e] = rk[b * EPB + e];

    // pre-scale keys by their reciprocal norm (folds rk out of the epilogue)
#pragma unroll
    for (int e = 0; e < EPB; ++e)
#pragma unroll
        for (int c = 0; c < 4; ++c) {
            kv[e][c].x *= rke[e]; kv[e][c].y *= rke[e];
            kv[e][c].z *= rke[e]; kv[e][c].w *= rke[e];
        }

    const int* mylist = list + (size_t)b * ntok;

    for (int i = q; i < n; i += 32) {
        int t = mylist[i];
        const float4* h4 = (const float4*)h + (size_t)t * 256;

        float4 hv[4];
        float hh = 0.f;
#pragma unroll
        for (int c = 0; c < 4; ++c) {
            hv[c] = h4[c * 64 + lane];
            hh += hv[c].x * hv[c].x + hv[c].y * hv[c].y +
                  hv[c].z * hv[c].z + hv[c].w * hv[c].w;
        }

        float dot[EPB];
#pragma unroll
        for (int e = 0; e < EPB; ++e) {
            float d = 0.f;
#pragma unroll
            for (int c = 0; c < 4; ++c)
                d += hv[c].x * kv[e][c].x + hv[c].y * kv[e][c].y +
                     hv[c].z * kv[e][c].z + hv[c].w * kv[e][c].w;
            dot[e] = d;
        }

#pragma unroll
        for (int off = 32; off; off >>= 1) {
            hh += __shfl_xor(hh, off, 64);
#pragma unroll
            for (int e = 0; e < EPB; ++e) dot[e] += __shfl_xor(dot[e], off, 64);
        }

        if (lane == 0) {
            float rh = 1.0f / fmaxf(sqrtf(hh), 1e-12f);
            float sc[EPB];
            float m = -1e30f;
#pragma unroll
            for (int e = 0; e < EPB; ++e) {
                sc[e] = dot[e] * rh;              // keys pre-scaled; TAU=1
                m = fmaxf(m, sc[e]);
            }
            float ex[EPB];
            float Z = 0.f;
#pragma unroll
            for (int e = 0; e < EPB; ++e) { ex[e] = expf(sc[e] - m); Z += ex[e]; }

            int i1 = 0;
#pragma unroll
            for (int e = 1; e < EPB; ++e) if (ex[e] > ex[i1]) i1 = e;
            int i2 = (i1 == 0) ? 1 : 0;
#pragma unroll
            for (int e = 0; e < EPB; ++e)
                if (e != i1 && ex[e] > ex[i2]) i2 = e;

            float p1 = ex[i1] / Z;
            float p2 = ex[i2] / Z;
            float wsum = p1 + p2 + 1e-9f;

            out_gid[(size_t)t * KTOP + 0] = (float)(b * EPB + i1);
            out_gid[(size_t)t * KTOP + 1] = (float)(b * EPB + i2);
            out_w  [(size_t)t * KTOP + 0] = p1 / wsum;
            out_w  [(size_t)t * KTOP + 1] = p2 / wsum;
        }
    }
}

extern "C" void kernel_launch(void* const* d_in, const int* in_sizes, int n_in,
                              void* d_out, int out_size, void* d_ws, size_t ws_size,
                              hipStream_t stream) {
    const float* h     = (const float*)d_in[0];
    const int*   op_id = (const int*)  d_in[1];
    const float* ek    = (const float*)d_in[2];

    int ntok  = in_sizes[1];           // B*T tokens
    int nrows = NB * EPB;              // 512 key rows

    // ws layout: rk (512 f) | cnt (64 i) | list (NB*ntok i)
    float* rk   = (float*)d_ws;
    int*   cnt  = (int*)(rk + 512);
    int*   list = cnt + 64;

    float* out_gid = (float*)d_out;
    float* out_w   = out_gid + (size_t)ntok * KTOP;

    int blocks1 = (nrows * 64 + 255) / 256;
    key_rnorm_kernel<<<blocks1, 256, 0, stream>>>(ek, rk, cnt, nrows);

    compact_kernel<<<(ntok + 255) / 256, 256, 0, stream>>>(op_id, cnt, list, ntok);

    // 8 blocks per bucket x 64 buckets = 512 blocks, 4 waves each
    router_kernel<<<NB * 8, 256, 0, stream>>>(h, ek, rk, cnt, list,
                                              out_gid, out_w, ntok);
}